// Round 2
// baseline (663.740 us; speedup 1.0000x reference)
//
#include <hip/hip_runtime.h>
#include <hip/hip_bf16.h>

// ---------------- helpers ----------------
typedef __attribute__((ext_vector_type(8))) short bf16x8;
typedef __attribute__((ext_vector_type(4))) float f32x4;

__device__ __forceinline__ float bf2f(unsigned short u) {
    unsigned int x = ((unsigned int)u) << 16;
    return __builtin_bit_cast(float, x);
}
__device__ __forceinline__ unsigned short f2bf(float f) {
    __hip_bfloat16 h = __float2bfloat16(f);   // round-to-nearest-even
    return __builtin_bit_cast(unsigned short, h);
}

// ---------------- CSR build ----------------
// NOTE: harness delivers integer inputs as int32 (edge_index int64 in the
// reference becomes int* here). Reading as long long caused the round-1 abort.
__global__ void k_hist(const int* __restrict__ dst, int* __restrict__ counts, int E) {
    int e = blockIdx.x * blockDim.x + threadIdx.x;
    if (e < E) atomicAdd(&counts[dst[e]], 1);
}

// single-block exclusive scan over NN counts -> row_start[NN+1], cursor copy
__global__ void k_scan(const int* __restrict__ counts, int* __restrict__ row_start,
                       int* __restrict__ cursor, int NN) {
    __shared__ int s[256];
    int t = threadIdx.x;
    int chunk = (NN + 255) / 256;
    int beg = t * chunk;
    int end = beg + chunk; if (end > NN) end = NN;
    int p = 0;
    for (int i = beg; i < end; ++i) p += counts[i];
    s[t] = p; __syncthreads();
    for (int off = 1; off < 256; off <<= 1) {
        int v = (t >= off) ? s[t - off] : 0;
        __syncthreads();
        s[t] += v;
        __syncthreads();
    }
    int run = s[t] - p;   // exclusive prefix
    for (int i = beg; i < end; ++i) {
        row_start[i] = run; cursor[i] = run; run += counts[i];
    }
    if (t == 255) row_start[NN] = run;   // == E
}

__global__ void k_fill(const int* __restrict__ src, const int* __restrict__ dst,
                       int* __restrict__ cursor, int* __restrict__ csrc, int E) {
    int e = blockIdx.x * blockDim.x + threadIdx.x;
    if (e < E) {
        int p = atomicAdd(&cursor[dst[e]], 1);
        csrc[p] = src[e];
    }
}

// ---------------- dtype conversions ----------------
__global__ void k_cvt_f2bf(const float* __restrict__ in, unsigned short* __restrict__ out, int n) {
    int i = blockIdx.x * blockDim.x + threadIdx.x;
    if (i < n) out[i] = f2bf(in[i]);
}

// W [K][N] fp32 -> Wt [N][K] bf16
__global__ void k_cvt_wt(const float* __restrict__ w, unsigned short* __restrict__ wt, int K, int N) {
    int i = blockIdx.x * blockDim.x + threadIdx.x;
    if (i < K * N) {
        int k = i / N, n = i - k * N;
        wt[n * K + k] = f2bf(w[i]);
    }
}

// ---------------- CSR aggregation: one wave per node ----------------
template <int F>
__global__ void k_agg(const unsigned short* __restrict__ h, const int* __restrict__ rs,
                      const int* __restrict__ csrc, unsigned short* __restrict__ out, int NN) {
    int gid = blockIdx.x * blockDim.x + threadIdx.x;
    int node = gid >> 6;
    if (node >= NN) return;
    int lane = gid & 63;
    int k0 = rs[node], k1 = rs[node + 1];
    if constexpr (F == 256) {
        float a0 = 0.f, a1 = 0.f, a2 = 0.f, a3 = 0.f;
        for (int k = k0; k < k1; ++k) {
            int s = csrc[k];
            ushort4 v = *((const ushort4*)(h + (size_t)s * 256) + lane);
            a0 += bf2f(v.x); a1 += bf2f(v.y); a2 += bf2f(v.z); a3 += bf2f(v.w);
        }
        ushort4 o; o.x = f2bf(a0); o.y = f2bf(a1); o.z = f2bf(a2); o.w = f2bf(a3);
        *((ushort4*)(out + (size_t)node * 256) + lane) = o;
    } else {  // F == 128
        float a0 = 0.f, a1 = 0.f;
        for (int k = k0; k < k1; ++k) {
            int s = csrc[k];
            ushort2 v = *((const ushort2*)(h + (size_t)s * 128) + lane);
            a0 += bf2f(v.x); a1 += bf2f(v.y);
        }
        ushort2 o; o.x = f2bf(a0); o.y = f2bf(a1);
        *((ushort2*)(out + (size_t)node * 128) + lane) = o;
    }
}

// ---------------- MFMA GEMM: C = relu(A @ W + b) ----------------
// A: [M][K] bf16 row-major.  Bt: [N][K] bf16 (W transposed).  N fixed = 256.
// Block: 256 threads (4 waves); tile 128(M) x 128(N); BK = 32.
#define BM 128
#define BN 128
#define BK 32
#define LDA 40   // padded row stride in shorts (32 + 8): breaks bank aliasing

template <bool OUT_BF16>
__global__ __launch_bounds__(256)
void k_gemm(const unsigned short* __restrict__ A, const unsigned short* __restrict__ Bt,
            const float* __restrict__ bias, void* __restrict__ Cout, int M, int K) {
    __shared__ unsigned short As[BM * LDA];
    __shared__ unsigned short Bs[BN * LDA];
    int tid = threadIdx.x;
    int mbase = blockIdx.x * BM;
    int nbase = blockIdx.y * BN;
    int w = tid >> 6, lane = tid & 63, quad = lane >> 4, l16 = lane & 15;

    f32x4 acc[2][8];
#pragma unroll
    for (int i = 0; i < 2; ++i)
#pragma unroll
        for (int j = 0; j < 8; ++j) acc[i][j] = (f32x4){0.f, 0.f, 0.f, 0.f};

    for (int kk0 = 0; kk0 < K; kk0 += BK) {
        // stage A tile: 128 rows x 32 k  (512 x 16B chunks)
        for (int c = tid; c < 512; c += 256) {
            int r = c >> 2, kk = (c & 3) * 8;
            int row = mbase + r; if (row >= M) row = M - 1;   // clamp; tail rows never stored
            uint4 v = *((const uint4*)(A + (size_t)row * K + kk0 + kk));
            *((uint4*)&As[r * LDA + kk]) = v;
        }
        // stage B tile: 128 n-rows x 32 k from Wt
        for (int c = tid; c < 512; c += 256) {
            int r = c >> 2, kk = (c & 3) * 8;
            uint4 v = *((const uint4*)(Bt + (size_t)(nbase + r) * K + kk0 + kk));
            *((uint4*)&Bs[r * LDA + kk]) = v;
        }
        __syncthreads();

        bf16x8 af[2], bfr[8];
#pragma unroll
        for (int mt = 0; mt < 2; ++mt) {
            int r = w * 32 + mt * 16 + l16;
            af[mt] = *((const bf16x8*)&As[r * LDA + quad * 8]);
        }
#pragma unroll
        for (int nt = 0; nt < 8; ++nt) {
            int n = nt * 16 + l16;
            bfr[nt] = *((const bf16x8*)&Bs[n * LDA + quad * 8]);
        }
#pragma unroll
        for (int mt = 0; mt < 2; ++mt)
#pragma unroll
            for (int nt = 0; nt < 8; ++nt)
                acc[mt][nt] = __builtin_amdgcn_mfma_f32_16x16x32_bf16(af[mt], bfr[nt], acc[mt][nt], 0, 0, 0);
        __syncthreads();
    }

    // epilogue: bias + relu, store.  C/D layout: col = lane&15, row = quad*4 + reg
#pragma unroll
    for (int mt = 0; mt < 2; ++mt) {
#pragma unroll
        for (int nt = 0; nt < 8; ++nt) {
            int n = nbase + nt * 16 + l16;
            float bv = bias[n];
#pragma unroll
            for (int r = 0; r < 4; ++r) {
                int m = mbase + w * 32 + mt * 16 + quad * 4 + r;
                if (m < M) {
                    float v = acc[mt][nt][r] + bv;
                    v = v > 0.f ? v : 0.f;
                    if (OUT_BF16)
                        ((unsigned short*)Cout)[(size_t)m * 256 + n] = f2bf(v);
                    else
                        ((float*)Cout)[(size_t)m * 256 + n] = v;
                }
            }
        }
    }
}

// ---------------- host ----------------
static inline size_t alignup(size_t x) { return (x + 255) & ~(size_t)255; }

extern "C" void kernel_launch(void* const* d_in, const int* in_sizes, int n_in,
                              void* d_out, int out_size, void* d_ws, size_t ws_size,
                              hipStream_t stream) {
    const float* x  = (const float*)d_in[0];
    const int* ei   = (const int*)d_in[1];    // int32 on device (harness converts)
    const float* W1 = (const float*)d_in[2];
    const float* b1 = (const float*)d_in[3];
    const float* W2 = (const float*)d_in[4];
    const float* b2 = (const float*)d_in[5];
    const float* W3 = (const float*)d_in[6];
    const float* b3 = (const float*)d_in[7];

    const int M = in_sizes[0] / 128;      // 50000 nodes
    const int E = in_sizes[1] / 2;        // 800000 edges
    const int* srcp = ei;
    const int* dstp = ei + E;

    // workspace carve-up (~43 MB). The h ping-pong buffer lives inside d_out:
    // h1/h2 (bf16, 25.6 MB) are dead before gemm3 overwrites d_out with fp32.
    char* p = (char*)d_ws;
    size_t off = 0;
    auto carve = [&](size_t bytes) { void* r = p + off; off += alignup(bytes); return r; };
    int* counts    = (int*)carve((size_t)M * 4);
    int* cursor    = (int*)carve((size_t)M * 4);
    int* row_start = (int*)carve((size_t)(M + 1) * 4);
    int* csrc      = (int*)carve((size_t)E * 4);
    unsigned short* w1t = (unsigned short*)carve((size_t)128 * 256 * 2);
    unsigned short* w2t = (unsigned short*)carve((size_t)256 * 256 * 2);
    unsigned short* w3t = (unsigned short*)carve((size_t)256 * 256 * 2);
    unsigned short* xb  = (unsigned short*)carve((size_t)M * 128 * 2);
    unsigned short* ab  = (unsigned short*)carve((size_t)M * 256 * 2);  // a1/a2/a3
    unsigned short* hb  = (unsigned short*)d_out;                        // h1/h2 (scratch in d_out)

    // 1) CSR build
    hipMemsetAsync(counts, 0, (size_t)M * 4, stream);
    k_hist<<<(E + 255) / 256, 256, 0, stream>>>(dstp, counts, E);
    k_scan<<<1, 256, 0, stream>>>(counts, row_start, cursor, M);
    k_fill<<<(E + 255) / 256, 256, 0, stream>>>(srcp, dstp, cursor, csrc, E);

    // 2) conversions
    int nx = M * 128;
    k_cvt_f2bf<<<(nx + 255) / 256, 256, 0, stream>>>(x, xb, nx);
    k_cvt_wt<<<(128 * 256 + 255) / 256, 256, 0, stream>>>(W1, w1t, 128, 256);
    k_cvt_wt<<<(256 * 256 + 255) / 256, 256, 0, stream>>>(W2, w2t, 256, 256);
    k_cvt_wt<<<(256 * 256 + 255) / 256, 256, 0, stream>>>(W3, w3t, 256, 256);

    dim3 ggrid((M + BM - 1) / BM, 2);

    // layer 1: a1 = agg(x); h1 = relu(a1 @ W1 + b1)
    k_agg<128><<<(M * 64 + 255) / 256, 256, 0, stream>>>(xb, row_start, csrc, ab, M);
    k_gemm<true><<<ggrid, 256, 0, stream>>>(ab, w1t, b1, hb, M, 128);

    // layer 2: a2 = agg(h1); h2 = relu(a2 @ W2 + b2)
    k_agg<256><<<(M * 64 + 255) / 256, 256, 0, stream>>>(hb, row_start, csrc, ab, M);
    k_gemm<true><<<ggrid, 256, 0, stream>>>(ab, w2t, b2, hb, M, 256);

    // layer 3: a3 = agg(h2); out = relu(a3 @ W3 + b3)
    k_agg<256><<<(M * 64 + 255) / 256, 256, 0, stream>>>(hb, row_start, csrc, ab, M);
    k_gemm<false><<<ggrid, 256, 0, stream>>>(ab, w3t, b3, d_out, M, 256);
}

// Round 3
// 549.364 us; speedup vs baseline: 1.2082x; 1.2082x over previous
//
#include <hip/hip_runtime.h>
#include <hip/hip_bf16.h>

// ---------------- helpers ----------------
typedef __attribute__((ext_vector_type(8))) short bf16x8;
typedef __attribute__((ext_vector_type(4))) float f32x4;

__device__ __forceinline__ float bf2f(unsigned short u) {
    unsigned int x = ((unsigned int)u) << 16;
    return __builtin_bit_cast(float, x);
}
__device__ __forceinline__ unsigned short f2bf(float f) {
    __hip_bfloat16 h = __float2bfloat16(f);   // round-to-nearest-even
    return __builtin_bit_cast(unsigned short, h);
}

// ---------------- CSR build ----------------
// Harness delivers integer inputs as int32 (edge_index int64 -> int*).
__global__ void k_hist(const int* __restrict__ dst, int* __restrict__ counts, int E) {
    int e = blockIdx.x * blockDim.x + threadIdx.x;
    if (e < E) atomicAdd(&counts[dst[e]], 1);
}

// Parallel scan, 3 kernels (single-block scan was 120 us = 18% of runtime).
// 1) per-block sums (256 elems/block, coalesced)
__global__ void k_psum(const int* __restrict__ counts, int* __restrict__ part, int NN) {
    __shared__ int s[256];
    int t = threadIdx.x;
    int i = blockIdx.x * 256 + t;
    s[t] = (i < NN) ? counts[i] : 0;
    __syncthreads();
    for (int off = 128; off > 0; off >>= 1) {
        if (t < off) s[t] += s[t + off];
        __syncthreads();
    }
    if (t == 0) part[blockIdx.x] = s[0];
}

// 2) exclusive scan of block partials (nb <= 256; NN=50000 -> nb=196)
__global__ void k_scanpart(int* __restrict__ part, int nb) {
    __shared__ int s[256];
    int t = threadIdx.x;
    int v = (t < nb) ? part[t] : 0;
    s[t] = v; __syncthreads();
    for (int off = 1; off < 256; off <<= 1) {
        int u = (t >= off) ? s[t - off] : 0;
        __syncthreads();
        s[t] += u;
        __syncthreads();
    }
    if (t < nb) part[t] = s[t] - v;   // exclusive
}

// 3) local scan + block offset -> row_start / cursor
__global__ void k_scatter_rs(const int* __restrict__ counts, const int* __restrict__ part,
                             int* __restrict__ row_start, int* __restrict__ cursor,
                             int NN, int E) {
    __shared__ int s[256];
    int t = threadIdx.x;
    int i = blockIdx.x * 256 + t;
    int v = (i < NN) ? counts[i] : 0;
    s[t] = v; __syncthreads();
    for (int off = 1; off < 256; off <<= 1) {
        int u = (t >= off) ? s[t - off] : 0;
        __syncthreads();
        s[t] += u;
        __syncthreads();
    }
    int ex = s[t] - v + part[blockIdx.x];
    if (i < NN) { row_start[i] = ex; cursor[i] = ex; }
    if (i == NN - 1) row_start[NN] = E;
}

__global__ void k_fill(const int* __restrict__ src, const int* __restrict__ dst,
                       int* __restrict__ cursor, int* __restrict__ csrc, int E) {
    int e = blockIdx.x * blockDim.x + threadIdx.x;
    if (e < E) {
        int p = atomicAdd(&cursor[dst[e]], 1);
        csrc[p] = src[e];
    }
}

// ---------------- dtype conversions ----------------
__global__ void k_cvt_f2bf(const float* __restrict__ in, unsigned short* __restrict__ out, int n) {
    int i = blockIdx.x * blockDim.x + threadIdx.x;
    if (i < n) out[i] = f2bf(in[i]);
}

// W [K][N] fp32 -> Wt [N][K] bf16
__global__ void k_cvt_wt(const float* __restrict__ w, unsigned short* __restrict__ wt, int K, int N) {
    int i = blockIdx.x * blockDim.x + threadIdx.x;
    if (i < K * N) {
        int k = i / N, n = i - k * N;
        wt[n * K + k] = f2bf(w[i]);
    }
}

// ---------------- CSR aggregation: one wave per node ----------------
template <int F>
__global__ void k_agg(const unsigned short* __restrict__ h, const int* __restrict__ rs,
                      const int* __restrict__ csrc, unsigned short* __restrict__ out, int NN) {
    int gid = blockIdx.x * blockDim.x + threadIdx.x;
    int node = gid >> 6;
    if (node >= NN) return;
    int lane = gid & 63;
    int k0 = rs[node], k1 = rs[node + 1];
    if constexpr (F == 256) {
        float a0 = 0.f, a1 = 0.f, a2 = 0.f, a3 = 0.f;
        for (int k = k0; k < k1; ++k) {
            int s = csrc[k];
            ushort4 v = *((const ushort4*)(h + (size_t)s * 256) + lane);
            a0 += bf2f(v.x); a1 += bf2f(v.y); a2 += bf2f(v.z); a3 += bf2f(v.w);
        }
        ushort4 o; o.x = f2bf(a0); o.y = f2bf(a1); o.z = f2bf(a2); o.w = f2bf(a3);
        *((ushort4*)(out + (size_t)node * 256) + lane) = o;
    } else {  // F == 128
        float a0 = 0.f, a1 = 0.f;
        for (int k = k0; k < k1; ++k) {
            int s = csrc[k];
            ushort2 v = *((const ushort2*)(h + (size_t)s * 128) + lane);
            a0 += bf2f(v.x); a1 += bf2f(v.y);
        }
        ushort2 o; o.x = f2bf(a0); o.y = f2bf(a1);
        *((ushort2*)(out + (size_t)node * 128) + lane) = o;
    }
}

// ---------------- MFMA GEMM: C = relu(A @ W + b) ----------------
// A: [M][K] bf16 row-major.  Bt: [N][K] bf16 (W transposed).  N fixed = 256.
// Block: 256 threads (4 waves); tile 128(M) x 128(N); BK = 32.
#define BM 128
#define BN 128
#define BK 32
#define LDA 40   // padded row stride in shorts (32 + 8): breaks bank aliasing

template <bool OUT_BF16>
__global__ __launch_bounds__(256)
void k_gemm(const unsigned short* __restrict__ A, const unsigned short* __restrict__ Bt,
            const float* __restrict__ bias, void* __restrict__ Cout, int M, int K) {
    __shared__ unsigned short As[BM * LDA];
    __shared__ unsigned short Bs[BN * LDA];
    int tid = threadIdx.x;
    int mbase = blockIdx.x * BM;
    int nbase = blockIdx.y * BN;
    int w = tid >> 6, lane = tid & 63, quad = lane >> 4, l16 = lane & 15;

    f32x4 acc[2][8];
#pragma unroll
    for (int i = 0; i < 2; ++i)
#pragma unroll
        for (int j = 0; j < 8; ++j) acc[i][j] = (f32x4){0.f, 0.f, 0.f, 0.f};

    for (int kk0 = 0; kk0 < K; kk0 += BK) {
        for (int c = tid; c < 512; c += 256) {
            int r = c >> 2, kk = (c & 3) * 8;
            int row = mbase + r; if (row >= M) row = M - 1;   // clamp; tail rows never stored
            uint4 v = *((const uint4*)(A + (size_t)row * K + kk0 + kk));
            *((uint4*)&As[r * LDA + kk]) = v;
        }
        for (int c = tid; c < 512; c += 256) {
            int r = c >> 2, kk = (c & 3) * 8;
            uint4 v = *((const uint4*)(Bt + (size_t)(nbase + r) * K + kk0 + kk));
            *((uint4*)&Bs[r * LDA + kk]) = v;
        }
        __syncthreads();

        bf16x8 af[2], bfr[8];
#pragma unroll
        for (int mt = 0; mt < 2; ++mt) {
            int r = w * 32 + mt * 16 + l16;
            af[mt] = *((const bf16x8*)&As[r * LDA + quad * 8]);
        }
#pragma unroll
        for (int nt = 0; nt < 8; ++nt) {
            int n = nt * 16 + l16;
            bfr[nt] = *((const bf16x8*)&Bs[n * LDA + quad * 8]);
        }
#pragma unroll
        for (int mt = 0; mt < 2; ++mt)
#pragma unroll
            for (int nt = 0; nt < 8; ++nt)
                acc[mt][nt] = __builtin_amdgcn_mfma_f32_16x16x32_bf16(af[mt], bfr[nt], acc[mt][nt], 0, 0, 0);
        __syncthreads();
    }

    // epilogue: bias + relu, store.  C/D layout: col = lane&15, row = quad*4 + reg
#pragma unroll
    for (int mt = 0; mt < 2; ++mt) {
#pragma unroll
        for (int nt = 0; nt < 8; ++nt) {
            int n = nbase + nt * 16 + l16;
            float bv = bias[n];
#pragma unroll
            for (int r = 0; r < 4; ++r) {
                int m = mbase + w * 32 + mt * 16 + quad * 4 + r;
                if (m < M) {
                    float v = acc[mt][nt][r] + bv;
                    v = v > 0.f ? v : 0.f;
                    if (OUT_BF16)
                        ((unsigned short*)Cout)[(size_t)m * 256 + n] = f2bf(v);
                    else
                        ((float*)Cout)[(size_t)m * 256 + n] = v;
                }
            }
        }
    }
}

// ---------------- host ----------------
static inline size_t alignup(size_t x) { return (x + 255) & ~(size_t)255; }

extern "C" void kernel_launch(void* const* d_in, const int* in_sizes, int n_in,
                              void* d_out, int out_size, void* d_ws, size_t ws_size,
                              hipStream_t stream) {
    const float* x  = (const float*)d_in[0];
    const int* ei   = (const int*)d_in[1];    // int32 on device (harness converts)
    const float* W1 = (const float*)d_in[2];
    const float* b1 = (const float*)d_in[3];
    const float* W2 = (const float*)d_in[4];
    const float* b2 = (const float*)d_in[5];
    const float* W3 = (const float*)d_in[6];
    const float* b3 = (const float*)d_in[7];

    const int M = in_sizes[0] / 128;      // 50000 nodes
    const int E = in_sizes[1] / 2;        // 800000 edges
    const int* srcp = ei;
    const int* dstp = ei + E;
    const int nscan = (M + 255) / 256;    // 196 partial-sum blocks

    // workspace carve-up (~43 MB). h ping-pong lives in d_out (dead before
    // gemm3 overwrites d_out with fp32).
    char* p = (char*)d_ws;
    size_t off = 0;
    auto carve = [&](size_t bytes) { void* r = p + off; off += alignup(bytes); return r; };
    int* counts    = (int*)carve((size_t)M * 4);
    int* cursor    = (int*)carve((size_t)M * 4);
    int* row_start = (int*)carve((size_t)(M + 1) * 4);
    int* part      = (int*)carve((size_t)256 * 4);
    int* csrc      = (int*)carve((size_t)E * 4);
    unsigned short* w1t = (unsigned short*)carve((size_t)128 * 256 * 2);
    unsigned short* w2t = (unsigned short*)carve((size_t)256 * 256 * 2);
    unsigned short* w3t = (unsigned short*)carve((size_t)256 * 256 * 2);
    unsigned short* xb  = (unsigned short*)carve((size_t)M * 128 * 2);
    unsigned short* ab  = (unsigned short*)carve((size_t)M * 256 * 2);  // a1/a2/a3
    unsigned short* hb  = (unsigned short*)d_out;                        // h1/h2

    // 1) CSR build (parallel scan)
    hipMemsetAsync(counts, 0, (size_t)M * 4, stream);
    k_hist<<<(E + 255) / 256, 256, 0, stream>>>(dstp, counts, E);
    k_psum<<<nscan, 256, 0, stream>>>(counts, part, M);
    k_scanpart<<<1, 256, 0, stream>>>(part, nscan);
    k_scatter_rs<<<nscan, 256, 0, stream>>>(counts, part, row_start, cursor, M, E);
    k_fill<<<(E + 255) / 256, 256, 0, stream>>>(srcp, dstp, cursor, csrc, E);

    // 2) conversions
    int nx = M * 128;
    k_cvt_f2bf<<<(nx + 255) / 256, 256, 0, stream>>>(x, xb, nx);
    k_cvt_wt<<<(128 * 256 + 255) / 256, 256, 0, stream>>>(W1, w1t, 128, 256);
    k_cvt_wt<<<(256 * 256 + 255) / 256, 256, 0, stream>>>(W2, w2t, 256, 256);
    k_cvt_wt<<<(256 * 256 + 255) / 256, 256, 0, stream>>>(W3, w3t, 256, 256);

    dim3 ggrid((M + BM - 1) / BM, 2);

    // layer 1: a1 = agg(x); h1 = relu(a1 @ W1 + b1)
    k_agg<128><<<(M * 64 + 255) / 256, 256, 0, stream>>>(xb, row_start, csrc, ab, M);
    k_gemm<true><<<ggrid, 256, 0, stream>>>(ab, w1t, b1, hb, M, 128);

    // layer 2: a2 = agg(h1); h2 = relu(a2 @ W2 + b2)
    k_agg<256><<<(M * 64 + 255) / 256, 256, 0, stream>>>(hb, row_start, csrc, ab, M);
    k_gemm<true><<<ggrid, 256, 0, stream>>>(ab, w2t, b2, hb, M, 256);

    // layer 3: a3 = agg(h2); out = relu(a3 @ W3 + b3)
    k_agg<256><<<(M * 64 + 255) / 256, 256, 0, stream>>>(hb, row_start, csrc, ab, M);
    k_gemm<false><<<ggrid, 256, 0, stream>>>(ab, w3t, b3, d_out, M, 256);
}

// Round 4
// 438.678 us; speedup vs baseline: 1.5130x; 1.2523x over previous
//
#include <hip/hip_runtime.h>
#include <hip/hip_bf16.h>

// ---------------- helpers ----------------
typedef __attribute__((ext_vector_type(8))) short bf16x8;
typedef __attribute__((ext_vector_type(4))) float f32x4;

__device__ __forceinline__ float bf2f(unsigned short u) {
    unsigned int x = ((unsigned int)u) << 16;
    return __builtin_bit_cast(float, x);
}
__device__ __forceinline__ unsigned short f2bf(float f) {
    __hip_bfloat16 h = __float2bfloat16(f);   // round-to-nearest-even
    return __builtin_bit_cast(unsigned short, h);
}
// accumulate a packed bf16 pair (low short -> x, high short -> y)
__device__ __forceinline__ void accp(float& x, float& y, unsigned int u) {
    x += __builtin_bit_cast(float, u << 16);
    y += __builtin_bit_cast(float, u & 0xffff0000u);
}
__device__ __forceinline__ unsigned int packbf(float lo, float hi) {
    return (unsigned int)f2bf(lo) | ((unsigned int)f2bf(hi) << 16);
}

// ---------------- CSR build ----------------
// Harness delivers integer inputs as int32 (edge_index int64 -> int*).
__global__ void k_hist(const int* __restrict__ dst, int* __restrict__ counts, int E) {
    int e = blockIdx.x * blockDim.x + threadIdx.x;
    if (e < E) atomicAdd(&counts[dst[e]], 1);
}

__global__ void k_psum(const int* __restrict__ counts, int* __restrict__ part, int NN) {
    __shared__ int s[256];
    int t = threadIdx.x;
    int i = blockIdx.x * 256 + t;
    s[t] = (i < NN) ? counts[i] : 0;
    __syncthreads();
    for (int off = 128; off > 0; off >>= 1) {
        if (t < off) s[t] += s[t + off];
        __syncthreads();
    }
    if (t == 0) part[blockIdx.x] = s[0];
}

__global__ void k_scanpart(int* __restrict__ part, int nb) {
    __shared__ int s[256];
    int t = threadIdx.x;
    int v = (t < nb) ? part[t] : 0;
    s[t] = v; __syncthreads();
    for (int off = 1; off < 256; off <<= 1) {
        int u = (t >= off) ? s[t - off] : 0;
        __syncthreads();
        s[t] += u;
        __syncthreads();
    }
    if (t < nb) part[t] = s[t] - v;   // exclusive
}

__global__ void k_scatter_rs(const int* __restrict__ counts, const int* __restrict__ part,
                             int* __restrict__ row_start, int* __restrict__ cursor,
                             int NN, int E) {
    __shared__ int s[256];
    int t = threadIdx.x;
    int i = blockIdx.x * 256 + t;
    int v = (i < NN) ? counts[i] : 0;
    s[t] = v; __syncthreads();
    for (int off = 1; off < 256; off <<= 1) {
        int u = (t >= off) ? s[t - off] : 0;
        __syncthreads();
        s[t] += u;
        __syncthreads();
    }
    int ex = s[t] - v + part[blockIdx.x];
    if (i < NN) { row_start[i] = ex; cursor[i] = ex; }
    if (i == NN - 1) row_start[NN] = E;
}

__global__ void k_fill(const int* __restrict__ src, const int* __restrict__ dst,
                       int* __restrict__ cursor, int* __restrict__ csrc, int E) {
    int e = blockIdx.x * blockDim.x + threadIdx.x;
    if (e < E) {
        int p = atomicAdd(&cursor[dst[e]], 1);
        csrc[p] = src[e];
    }
}

// ---------------- dtype conversions ----------------
__global__ void k_cvt_f2bf4(const float4* __restrict__ in, ushort4* __restrict__ out, int n4) {
    int i = blockIdx.x * blockDim.x + threadIdx.x;
    if (i < n4) {
        float4 v = in[i];
        ushort4 o; o.x = f2bf(v.x); o.y = f2bf(v.y); o.z = f2bf(v.z); o.w = f2bf(v.w);
        out[i] = o;
    }
}

// W [K][N] fp32 -> Wt [N][K] bf16
__global__ void k_cvt_wt(const float* __restrict__ w, unsigned short* __restrict__ wt, int K, int N) {
    int i = blockIdx.x * blockDim.x + threadIdx.x;
    if (i < K * N) {
        int k = i / N, n = i - k * N;
        wt[n * K + k] = f2bf(w[i]);
    }
}

// ---------------- CSR aggregation ----------------
// One wave per node. 2 edges per wave-iteration (32 lanes each), 2-way unroll
// with independent accumulator banks -> 4 row-gathers in flight per wave.
// Indices are pre-loaded coalesced and broadcast via shfl (no index load on
// the dependent chain).
template <int F>   // 256: 16 B/lane rows; 128: 8 B/lane rows
__global__ void k_agg(const unsigned short* __restrict__ h, const int* __restrict__ rs,
                      const int* __restrict__ csrc, unsigned short* __restrict__ out, int NN) {
    int gid = blockIdx.x * blockDim.x + threadIdx.x;
    int node = gid >> 6;
    if (node >= NN) return;
    int lane = threadIdx.x & 63;
    int half = lane >> 5, l32 = lane & 31;
    int k0 = rs[node], k1 = rs[node + 1];
    int cnt = k1 - k0;

    constexpr int NV = (F == 256) ? 8 : 4;   // fp32 accumulators per lane
    float a0[NV], a1[NV];
#pragma unroll
    for (int i = 0; i < NV; ++i) { a0[i] = 0.f; a1[i] = 0.f; }

    for (int base = 0; base < cnt; base += 64) {
        int nk = min(cnt - base, 64);
        int myidx = (lane < nk) ? csrc[k0 + base + lane] : 0;
        int j = 0;
        for (; j + 4 <= nk; j += 4) {
            int s0 = __shfl(myidx, j + half, 64);
            int s1 = __shfl(myidx, j + 2 + half, 64);
            if constexpr (F == 256) {
                uint4 v0 = ((const uint4*)(h + (size_t)s0 * F))[l32];
                uint4 v1 = ((const uint4*)(h + (size_t)s1 * F))[l32];
                accp(a0[0], a0[1], v0.x); accp(a0[2], a0[3], v0.y);
                accp(a0[4], a0[5], v0.z); accp(a0[6], a0[7], v0.w);
                accp(a1[0], a1[1], v1.x); accp(a1[2], a1[3], v1.y);
                accp(a1[4], a1[5], v1.z); accp(a1[6], a1[7], v1.w);
            } else {
                uint2 v0 = ((const uint2*)(h + (size_t)s0 * F))[l32];
                uint2 v1 = ((const uint2*)(h + (size_t)s1 * F))[l32];
                accp(a0[0], a0[1], v0.x); accp(a0[2], a0[3], v0.y);
                accp(a1[0], a1[1], v1.x); accp(a1[2], a1[3], v1.y);
            }
        }
        for (; j < nk; j += 2) {
            int jj = j + half;
            int s = __shfl(myidx, jj < nk ? jj : 0, 64);   // shfl before divergence
            if (jj < nk) {
                if constexpr (F == 256) {
                    uint4 v = ((const uint4*)(h + (size_t)s * F))[l32];
                    accp(a0[0], a0[1], v.x); accp(a0[2], a0[3], v.y);
                    accp(a0[4], a0[5], v.z); accp(a0[6], a0[7], v.w);
                } else {
                    uint2 v = ((const uint2*)(h + (size_t)s * F))[l32];
                    accp(a0[0], a0[1], v.x); accp(a0[2], a0[3], v.y);
                }
            }
        }
    }

    // combine banks, then fold upper half into lower
#pragma unroll
    for (int i = 0; i < NV; ++i) a0[i] += a1[i];
#pragma unroll
    for (int i = 0; i < NV; ++i) {
        float other = __shfl(a0[i], l32 + 32, 64);
        a0[i] += other;                         // valid for lanes 0..31
    }
    if (half == 0) {
        if constexpr (F == 256) {
            uint4 o;
            o.x = packbf(a0[0], a0[1]); o.y = packbf(a0[2], a0[3]);
            o.z = packbf(a0[4], a0[5]); o.w = packbf(a0[6], a0[7]);
            ((uint4*)(out + (size_t)node * F))[l32] = o;
        } else {
            uint2 o;
            o.x = packbf(a0[0], a0[1]); o.y = packbf(a0[2], a0[3]);
            ((uint2*)(out + (size_t)node * F))[l32] = o;
        }
    }
}

// ---------------- MFMA GEMM: C = relu(A @ W + b) ----------------
#define BM 128
#define BN 128
#define BK 32
#define LDA 40   // padded row stride in shorts

template <bool OUT_BF16>
__global__ __launch_bounds__(256)
void k_gemm(const unsigned short* __restrict__ A, const unsigned short* __restrict__ Bt,
            const float* __restrict__ bias, void* __restrict__ Cout, int M, int K) {
    __shared__ unsigned short As[BM * LDA];
    __shared__ unsigned short Bs[BN * LDA];
    int tid = threadIdx.x;
    int mbase = blockIdx.x * BM;
    int nbase = blockIdx.y * BN;
    int w = tid >> 6, lane = tid & 63, quad = lane >> 4, l16 = lane & 15;

    f32x4 acc[2][8];
#pragma unroll
    for (int i = 0; i < 2; ++i)
#pragma unroll
        for (int j = 0; j < 8; ++j) acc[i][j] = (f32x4){0.f, 0.f, 0.f, 0.f};

    for (int kk0 = 0; kk0 < K; kk0 += BK) {
        for (int c = tid; c < 512; c += 256) {
            int r = c >> 2, kk = (c & 3) * 8;
            int row = mbase + r; if (row >= M) row = M - 1;   // clamp; tail rows never stored
            uint4 v = *((const uint4*)(A + (size_t)row * K + kk0 + kk));
            *((uint4*)&As[r * LDA + kk]) = v;
        }
        for (int c = tid; c < 512; c += 256) {
            int r = c >> 2, kk = (c & 3) * 8;
            uint4 v = *((const uint4*)(Bt + (size_t)(nbase + r) * K + kk0 + kk));
            *((uint4*)&Bs[r * LDA + kk]) = v;
        }
        __syncthreads();

        bf16x8 af[2], bfr[8];
#pragma unroll
        for (int mt = 0; mt < 2; ++mt) {
            int r = w * 32 + mt * 16 + l16;
            af[mt] = *((const bf16x8*)&As[r * LDA + quad * 8]);
        }
#pragma unroll
        for (int nt = 0; nt < 8; ++nt) {
            int n = nt * 16 + l16;
            bfr[nt] = *((const bf16x8*)&Bs[n * LDA + quad * 8]);
        }
#pragma unroll
        for (int mt = 0; mt < 2; ++mt)
#pragma unroll
            for (int nt = 0; nt < 8; ++nt)
                acc[mt][nt] = __builtin_amdgcn_mfma_f32_16x16x32_bf16(af[mt], bfr[nt], acc[mt][nt], 0, 0, 0);
        __syncthreads();
    }

    // epilogue: bias + relu.  C/D layout: col = lane&15, row = quad*4 + reg
#pragma unroll
    for (int mt = 0; mt < 2; ++mt) {
#pragma unroll
        for (int nt = 0; nt < 8; ++nt) {
            int n = nbase + nt * 16 + l16;
            float bv = bias[n];
#pragma unroll
            for (int r = 0; r < 4; ++r) {
                int m = mbase + w * 32 + mt * 16 + quad * 4 + r;
                if (m < M) {
                    float v = acc[mt][nt][r] + bv;
                    v = v > 0.f ? v : 0.f;
                    if (OUT_BF16)
                        ((unsigned short*)Cout)[(size_t)m * 256 + n] = f2bf(v);
                    else
                        ((float*)Cout)[(size_t)m * 256 + n] = v;
                }
            }
        }
    }
}

// ---------------- host ----------------
static inline size_t alignup(size_t x) { return (x + 255) & ~(size_t)255; }

extern "C" void kernel_launch(void* const* d_in, const int* in_sizes, int n_in,
                              void* d_out, int out_size, void* d_ws, size_t ws_size,
                              hipStream_t stream) {
    const float* x  = (const float*)d_in[0];
    const int* ei   = (const int*)d_in[1];    // int32 on device (harness converts)
    const float* W1 = (const float*)d_in[2];
    const float* b1 = (const float*)d_in[3];
    const float* W2 = (const float*)d_in[4];
    const float* b2 = (const float*)d_in[5];
    const float* W3 = (const float*)d_in[6];
    const float* b3 = (const float*)d_in[7];

    const int M = in_sizes[0] / 128;      // 50000 nodes
    const int E = in_sizes[1] / 2;        // 800000 edges
    const int* srcp = ei;
    const int* dstp = ei + E;
    const int nscan = (M + 255) / 256;

    // workspace carve-up (~43 MB). h ping-pong lives in d_out (dead before
    // gemm3 overwrites d_out with fp32).
    char* p = (char*)d_ws;
    size_t off = 0;
    auto carve = [&](size_t bytes) { void* r = p + off; off += alignup(bytes); return r; };
    int* counts    = (int*)carve((size_t)M * 4);
    int* cursor    = (int*)carve((size_t)M * 4);
    int* row_start = (int*)carve((size_t)(M + 1) * 4);
    int* part      = (int*)carve((size_t)256 * 4);
    int* csrc      = (int*)carve((size_t)E * 4);
    unsigned short* w1t = (unsigned short*)carve((size_t)128 * 256 * 2);
    unsigned short* w2t = (unsigned short*)carve((size_t)256 * 256 * 2);
    unsigned short* w3t = (unsigned short*)carve((size_t)256 * 256 * 2);
    unsigned short* xb  = (unsigned short*)carve((size_t)M * 128 * 2);
    unsigned short* ab  = (unsigned short*)carve((size_t)M * 256 * 2);  // a1/a2/a3
    unsigned short* hb  = (unsigned short*)d_out;                        // h1/h2

    // 1) CSR build (parallel scan)
    hipMemsetAsync(counts, 0, (size_t)M * 4, stream);
    k_hist<<<(E + 255) / 256, 256, 0, stream>>>(dstp, counts, E);
    k_psum<<<nscan, 256, 0, stream>>>(counts, part, M);
    k_scanpart<<<1, 256, 0, stream>>>(part, nscan);
    k_scatter_rs<<<nscan, 256, 0, stream>>>(counts, part, row_start, cursor, M, E);
    k_fill<<<(E + 255) / 256, 256, 0, stream>>>(srcp, dstp, cursor, csrc, E);

    // 2) conversions
    int n4 = M * 128 / 4;
    k_cvt_f2bf4<<<(n4 + 255) / 256, 256, 0, stream>>>((const float4*)x, (ushort4*)xb, n4);
    k_cvt_wt<<<(128 * 256 + 255) / 256, 256, 0, stream>>>(W1, w1t, 128, 256);
    k_cvt_wt<<<(256 * 256 + 255) / 256, 256, 0, stream>>>(W2, w2t, 256, 256);
    k_cvt_wt<<<(256 * 256 + 255) / 256, 256, 0, stream>>>(W3, w3t, 256, 256);

    dim3 ggrid((M + BM - 1) / BM, 2);
    int aggblocks = (M * 64 + 255) / 256;

    // layer 1: a1 = agg(x); h1 = relu(a1 @ W1 + b1)
    k_agg<128><<<aggblocks, 256, 0, stream>>>(xb, row_start, csrc, ab, M);
    k_gemm<true><<<ggrid, 256, 0, stream>>>(ab, w1t, b1, hb, M, 128);

    // layer 2: a2 = agg(h1); h2 = relu(a2 @ W2 + b2)
    k_agg<256><<<aggblocks, 256, 0, stream>>>(hb, row_start, csrc, ab, M);
    k_gemm<true><<<ggrid, 256, 0, stream>>>(ab, w2t, b2, hb, M, 256);

    // layer 3: a3 = agg(h2); out = relu(a3 @ W3 + b3)
    k_agg<256><<<aggblocks, 256, 0, stream>>>(hb, row_start, csrc, ab, M);
    k_gemm<false><<<ggrid, 256, 0, stream>>>(ab, w3t, b3, d_out, M, 256);
}